// Round 8
// baseline (53.186 us; speedup 1.0000x reference)
//
#include <hip/hip_runtime.h>

// Problem constants (from reference setup_inputs)
#define B_DIM 8
#define F_DIM 16384
#define K_DIM 3
#define M_DIM 64
#define MCH   16                 // m-values per block in feat kernel
#define LOG2E 1.4426950408889634f

// ws float layout (deterministic, fully overwritten every launch):
//   [0, 16384)     : partial sums   slot = m*256 + b*32 + fc
//   [16384, 32768) : partial sumsq  (same indexing)
// Each partial = sum over one block's 512 f-values for channel m.
#define WS_Q 16384

// ---------------------------------------------------------------------------
// Kernel 1: feat[b,m,f] (pre-BN) -> d_out, plus per-(m,b,fc) partial
// sum/sumsq -> ws. grid = 1024 (8 b * 4 mc * 32 fc), block = 256.
// Each thread owns TWO consecutive f (float2 loads/stores): halves per-element
// address arithmetic + shuffle count, doubles exp-chain ILP (R7 showed feat
// issues ~2.5x the counted math ops -> overhead-bound).
// ---------------------------------------------------------------------------
__global__ __launch_bounds__(256, 4) void fkc_feat_kernel(
    const float* __restrict__ normals,   // [B,3,F]
    const float* __restrict__ walpha,    // [M*4]
    const float* __restrict__ wbeta,     // [M*4]
    const int*   __restrict__ nidx,      // [B,F,K] int32
    float* __restrict__ feat_out,        // [B,M,F]
    float* __restrict__ ws)
{
    __shared__ float4 sW[MCH * 4];
    __shared__ float sRS[MCH][32];       // [m][wave*8 + class]
    __shared__ float sRQ[MCH][32];

    const int tid = threadIdx.x;
    const int b  = blockIdx.x >> 7;          // 128 blocks per batch
    const int mc = (blockIdx.x >> 5) & 3;    // m-chunk
    const int fc = blockIdx.x & 31;          // f-chunk (512 f)

    // Kernel-point table. ||p||^2 == 1 (unit normals), folded into .w:
    // arg_log2 = 25*log2e*dot - 12.5*log2e*(1 + ||w||^2)
    if (tid < MCH * 4) {
        int idx = mc * MCH * 4 + tid;
        float a = walpha[idx], bb = wbeta[idx];
        float sa = sinf(a), ca = cosf(a);
        float sb = sinf(bb), cb = cosf(bb);
        float wx = sa * cb, wy = sa * sb, wz = ca;
        float w2 = wx * wx + wy * wy + wz * wz;
        sW[tid] = make_float4(wx * 25.0f * LOG2E, wy * 25.0f * LOG2E,
                              wz * 25.0f * LOG2E, -12.5f * LOG2E * (w2 + 1.0f));
    }
    __syncthreads();

    const int f0 = (fc << 9) + tid * 2;      // two consecutive f per thread
    const float* nb = normals + (size_t)b * 3 * F_DIM;

    // Center points for f0 (A) and f0+1 (B): float2 vector loads.
    float pxA[4], pyA[4], pzA[4], pxB[4], pyB[4], pzB[4];
    {
        float2 vx = *(const float2*)(nb + f0);
        float2 vy = *(const float2*)(nb + F_DIM + f0);
        float2 vz = *(const float2*)(nb + 2 * F_DIM + f0);
        pxA[0] = vx.x; pxB[0] = vx.y;
        pyA[0] = vy.x; pyB[0] = vy.y;
        pzA[0] = vz.x; pzB[0] = vz.y;
    }
    // Neighbor gathers (scalar, cache-served).
    {
        const int* ib = nidx + ((size_t)b * F_DIM + f0) * K_DIM;
#pragma unroll
        for (int k = 0; k < K_DIM; ++k) {
            int id = ib[k];
            pxA[k + 1] = nb[id]; pyA[k + 1] = nb[F_DIM + id]; pzA[k + 1] = nb[2 * F_DIM + id];
            id = ib[k + 3];
            pxB[k + 1] = nb[id]; pyB[k + 1] = nb[F_DIM + id]; pzB[k + 1] = nb[2 * F_DIM + id];
        }
    }

    const int wave = tid >> 6, lane = tid & 63;
    float* outb = feat_out + ((size_t)b * M_DIM + mc * MCH) * F_DIM + f0;
#pragma unroll 2
    for (int m = 0; m < MCH; ++m) {
        float a0 = 0.f, a1 = 0.f, a2 = 0.f, a3 = 0.f;
        float b0 = 0.f, b1 = 0.f, b2 = 0.f, b3 = 0.f;
#pragma unroll
        for (int j = 0; j < 4; ++j) {
            float4 w = sW[m * 4 + j];
            a0 += __builtin_amdgcn_exp2f(fmaf(w.x, pxA[0], fmaf(w.y, pyA[0], fmaf(w.z, pzA[0], w.w))));
            a1 += __builtin_amdgcn_exp2f(fmaf(w.x, pxA[1], fmaf(w.y, pyA[1], fmaf(w.z, pzA[1], w.w))));
            a2 += __builtin_amdgcn_exp2f(fmaf(w.x, pxA[2], fmaf(w.y, pyA[2], fmaf(w.z, pzA[2], w.w))));
            a3 += __builtin_amdgcn_exp2f(fmaf(w.x, pxA[3], fmaf(w.y, pyA[3], fmaf(w.z, pzA[3], w.w))));
            b0 += __builtin_amdgcn_exp2f(fmaf(w.x, pxB[0], fmaf(w.y, pyB[0], fmaf(w.z, pzB[0], w.w))));
            b1 += __builtin_amdgcn_exp2f(fmaf(w.x, pxB[1], fmaf(w.y, pyB[1], fmaf(w.z, pzB[1], w.w))));
            b2 += __builtin_amdgcn_exp2f(fmaf(w.x, pxB[2], fmaf(w.y, pyB[2], fmaf(w.z, pzB[2], w.w))));
            b3 += __builtin_amdgcn_exp2f(fmaf(w.x, pxB[3], fmaf(w.y, pyB[3], fmaf(w.z, pzB[3], w.w))));
        }
        float fA = ((a0 + a1) + (a2 + a3)) * (1.0f / 16.0f);
        float fB = ((b0 + b1) + (b2 + b3)) * (1.0f / 16.0f);
        *(float2*)(outb + (size_t)m * F_DIM) = make_float2(fA, fB);

        // 3-step butterfly (offs 8/16/32): lanes 0-7 hold 8 class sums.
        float s = fA + fB;
        float q = fA * fA + fB * fB;
        s += __shfl_xor(s, 8, 64);  q += __shfl_xor(q, 8, 64);
        s += __shfl_xor(s, 16, 64); q += __shfl_xor(q, 16, 64);
        s += __shfl_xor(s, 32, 64); q += __shfl_xor(q, 32, 64);
        if (lane < 8) { sRS[m][wave * 8 + lane] = s; sRQ[m][wave * 8 + lane] = q; }
    }
    __syncthreads();

    // Fold 32 class-sums per m: thread t -> (m = t>>4, j = t&15).
    {
        const int m = tid >> 4, j = tid & 15;
        float s = sRS[m][j] + sRS[m][j + 16];
        float q = sRQ[m][j] + sRQ[m][j + 16];
        s += __shfl_xor(s, 1, 64);  q += __shfl_xor(q, 1, 64);
        s += __shfl_xor(s, 2, 64);  q += __shfl_xor(q, 2, 64);
        s += __shfl_xor(s, 4, 64);  q += __shfl_xor(q, 4, 64);
        s += __shfl_xor(s, 8, 64);  q += __shfl_xor(q, 8, 64);
        if (j == 0) {
            int slot = (mc * MCH + m) * 256 + b * 32 + fc;
            ws[slot] = s;
            ws[WS_Q + slot] = q;
        }
    }
}

// ---------------------------------------------------------------------------
// Kernel 2: stats + BN + ReLU. grid = B*M = 512 blocks, one (b,m) row each.
// Phase A: fold this channel's 256 partials (1 KB, L2-hot) -> A, C.
// Phase B: stream the 64 KB row in place with float4 (near HBM floor).
// ---------------------------------------------------------------------------
__global__ __launch_bounds__(256) void fkc_bn_kernel(
    float* __restrict__ out,             // [B,M,F]
    const float* __restrict__ gamma,
    const float* __restrict__ beta,
    const float* __restrict__ ws)
{
    __shared__ float sS[4], sQ[4];
    __shared__ float sAC[2];
    const int row = blockIdx.x;              // b*64 + m
    const int m = row & 63;
    const int tid = threadIdx.x;
    const int wave = tid >> 6, lane = tid & 63;

    // Phase A: reduce 256 partials (one per thread).
    {
        float s = ws[m * 256 + tid];
        float q = ws[WS_Q + m * 256 + tid];
#pragma unroll
        for (int off = 32; off >= 1; off >>= 1) {
            s += __shfl_xor(s, off, 64);
            q += __shfl_xor(q, off, 64);
        }
        if (lane == 0) { sS[wave] = s; sQ[wave] = q; }
    }
    __syncthreads();
    if (tid == 0) {
        float s = (sS[0] + sS[1]) + (sS[2] + sS[3]);
        float q = (sQ[0] + sQ[1]) + (sQ[2] + sQ[3]);
        const float invcnt = 1.0f / (float)(B_DIM * F_DIM);
        float mean = s * invcnt;
        float var  = q * invcnt - mean * mean;
        float inv  = rsqrtf(var + 1e-5f);
        float A = gamma[m] * inv;
        sAC[0] = A;
        sAC[1] = beta[m] - mean * A;
    }
    __syncthreads();

    // Phase B: BN + ReLU over this row, float4.
    const float A = sAC[0], C = sAC[1];
    float4* p4 = (float4*)(out + (size_t)row * F_DIM);
#pragma unroll
    for (int i = 0; i < 16; ++i) {           // 4096 float4 / 256 threads
        float4 v = p4[tid + i * 256];
        v.x = fmaxf(fmaf(v.x, A, C), 0.0f);
        v.y = fmaxf(fmaf(v.y, A, C), 0.0f);
        v.z = fmaxf(fmaf(v.z, A, C), 0.0f);
        v.w = fmaxf(fmaf(v.w, A, C), 0.0f);
        p4[tid + i * 256] = v;
    }
}

// ---------------------------------------------------------------------------
extern "C" void kernel_launch(void* const* d_in, const int* in_sizes, int n_in,
                              void* d_out, int out_size, void* d_ws, size_t ws_size,
                              hipStream_t stream)
{
    const float* normals = (const float*)d_in[0];
    const float* walpha  = (const float*)d_in[1];
    const float* wbeta   = (const float*)d_in[2];
    const float* gamma   = (const float*)d_in[3];
    const float* beta    = (const float*)d_in[4];
    const int*   nidx    = (const int*)d_in[5];
    float* out = (float*)d_out;
    float* ws  = (float*)d_ws;

    // 2 dispatches. No memset, no atomics: every ws slot used is
    // overwritten every launch (poison-safe).
    hipLaunchKernelGGL(fkc_feat_kernel, dim3(1024), dim3(256), 0, stream,
                       normals, walpha, wbeta, nidx, out, ws);
    hipLaunchKernelGGL(fkc_bn_kernel, dim3(B_DIM * M_DIM), dim3(256), 0, stream,
                       out, gamma, beta, ws);
}